// Round 14
// baseline (719.936 us; speedup 1.0000x reference)
//
#include <hip/hip_runtime.h>

typedef _Float16 f16;
typedef _Float16 half8 __attribute__((ext_vector_type(8)));
typedef float f32x4 __attribute__((ext_vector_type(4)));

__device__ __forceinline__ void gl_lds16(const void* g, void* l) {
  __builtin_amdgcn_global_load_lds(
      (__attribute__((address_space(1))) void*)(size_t)g,
      (__attribute__((address_space(3))) void*)l, 16, 0, 0);
}

// ---------------------------------------------------------------------------
// 128x256 GEMM (BM=128 so TWO blocks fit per CU: 76KB LDS, <=128 VGPR at
// __launch_bounds__(512,4); r13's 1-block/CU = 8 lockstep waves was the
// structural wall — all schedules converged to ~2x the service floor because
// no co-resident block covered the stalls).  Ring-3 x 24KB slots, r12-proven
// 2-phase counted-vmcnt schedule with re-derived counts (3 gl_lds/K-step):
//  Phase A: {read af[0-3],bf0,bf1(+BN) | stageA(kt+2) | BAR | lgkm0 | BNA |
//            setprio 8 MFMA (n0,n1)}
//  Phase B: {read bf2,bf3 | stageB(kt+2) | vmcnt(3) | BAR | lgkm0 |
//            setprio 8 MFMA (n2,n3)}
// vmcnt(3) certifies slot (kt+1)%3 (stage kt+2's 3 ops stay in flight);
// tail vmcnt(0) at kt==Ksteps-2.  Prologue: table + slots 0..2, vmcnt(6).
// K-TILED operands (r13): elem(m,k) at (m>>8)*256*KP + (k>>5)*8192 +
// (m&255)*32 + (k&31); BM=128 A-halves are contiguous 8KB in a panel chunk.
// EPI 0/1: f16 out K-tiled + (EPI0) per-(tile,wm,lg) stats.  EPI 2: f32.
// BNA 1: fused BatchNorm+ReLU from LDS tables.  Ksteps >= 3.
// ---------------------------------------------------------------------------
template <int EPI, int BNA>
__global__ __launch_bounds__(512, 4) void gemm128_k(
    const f16* __restrict__ A, int Ksteps, int KP,
    void* __restrict__ outp, int ldOut, int Ncols,
    float2* __restrict__ partial, int r1, int kz, int oz,
    const f16* __restrict__ B0, const float* __restrict__ bias0,
    const f16* __restrict__ sc0, const f16* __restrict__ sh0,
    const f16* __restrict__ B1, const float* __restrict__ bias1,
    const f16* __restrict__ sc1, const f16* __restrict__ sh1) {
  __shared__ char smem[77824];  // 3 x 24KB slots + 2x2KB BN tables

  const int t = threadIdx.x;
  const int lane = t & 63;
  const int wave = t >> 6;
  const int wm = wave >> 2, wn = wave & 3;  // 2M x 4N, per-wave 64x64
  const int l16 = lane & 15, lg = lane >> 4;

  // bijective XCD-chunked swizzle (x*y grids here have nwg % 8 == 0)
  int bx = blockIdx.x, by = blockIdx.y;
  {
    const int nwg = gridDim.x * gridDim.y;
    const int wg = bx + gridDim.x * by;
    const int cpx = nwg >> 3;
    const int newid = (wg & 7) * cpx + (wg >> 3);
    bx = newid % gridDim.x;
    by = newid / gridDim.x;
  }
  const int m0 = by * 128;
  const int n0 = bx * 256;

  const f16* Bw = (by >= r1) ? B1 : B0;
  const float* bias = (by >= r1) ? bias1 : bias0;
  const f16* scH = (by >= r1) ? sc1 : sc0;
  const f16* shH = (by >= r1) ? sh1 : sh0;

  f32x4 acc[4][4] = {};

  // staging: thread t covers row t>>2 (A: 0..127; B: also +128), slot t&3;
  // LDS[r][s] holds k-chunk s ^ ((r>>1)&3) (inverse-swizzled source).
  const int rA = t >> 2;
  const int g16 = ((t & 3) ^ ((t >> 3) & 3)) * 16;
  const f16* Apan = A + (size_t)(m0 >> 8) * 256 * KP + (size_t)blockIdx.z * kz;
  const f16* Bpan = Bw + (size_t)(n0 >> 8) * 256 * KP + (size_t)blockIdx.z * kz;
  const char* gA = (const char*)Apan + (m0 & 255) * 64 + rA * 64 + g16;
  const char* gB = (const char*)Bpan + rA * 64 + g16;

  auto stageA = [&](int slot, int kt) {  // 8KB: 1 gl_lds per thread
    gl_lds16(gA + (size_t)kt * 16384, smem + slot * 24576 + t * 16);
  };
  auto stageB = [&](int slot, int kt) {  // 16KB: 2 gl_lds per thread
    const char* p = gB + (size_t)kt * 16384;
    char* d = smem + slot * 24576 + 8192 + t * 16;
    gl_lds16(p, d);
    gl_lds16(p + 8192, d + 8192);
  };

  // ---- prologue: BN table FIRST (skew retires in vmcnt), then slots 0..2
  if constexpr (BNA) {
    if (t < 128)
      gl_lds16((const char*)scH + t * 16, smem + 73728 + t * 16);
    else if (t < 256)
      gl_lds16((const char*)shH + (t - 128) * 16, smem + 75776 + (t - 128) * 16);
  }
  stageA(0, 0);
  stageB(0, 0);
  stageA(1, 1);
  stageB(1, 1);
  stageA(2, 2);
  stageB(2, 2);
  asm volatile("s_waitcnt vmcnt(6)" ::: "memory");  // slot0 (+table) landed
  __builtin_amdgcn_s_barrier();
  asm volatile("" ::: "memory");

  // per-lane constant LDS fragment bases
  const int xsw = (lg ^ ((l16 >> 1) & 3)) << 4;
  const int oA0 = (wm * 64 + l16) * 64 + xsw;          // + m*1024
  const int oB0 = 8192 + (wn * 64 + l16) * 64 + xsw;   // + n*1024

  for (int kt = 0; kt < Ksteps; ++kt) {
    const int slot = kt % 3;
    const char* buf = smem + slot * 24576;
    // ---- phase A: reads | stageA(kt+2) | BAR | lgkm0 | BNA | MFMA n0,n1
    half8 af[4], bf0, bf1, scv, shv;
#pragma unroll
    for (int m = 0; m < 4; ++m) af[m] = *(const half8*)(buf + oA0 + m * 1024);
    bf0 = *(const half8*)(buf + oB0);
    bf1 = *(const half8*)(buf + oB0 + 1024);
    if constexpr (BNA) {
      scv = *(const half8*)(smem + 73728 + kt * 64 + lg * 16);
      shv = *(const half8*)(smem + 75776 + kt * 64 + lg * 16);
    }
    if (kt + 2 < Ksteps) stageA((kt + 2) % 3, kt + 2);
    asm volatile("" ::: "memory");
    __builtin_amdgcn_s_barrier();
    asm volatile("s_waitcnt lgkmcnt(0)" ::: "memory");
    if constexpr (BNA) {
      const half8 zeroh = {};
#pragma unroll
      for (int m = 0; m < 4; ++m)
        af[m] = __builtin_elementwise_max((half8)(af[m] * scv + shv), zeroh);
    }
    __builtin_amdgcn_s_setprio(1);
#pragma unroll
    for (int m = 0; m < 4; ++m) {
      acc[m][0] = __builtin_amdgcn_mfma_f32_16x16x32_f16(af[m], bf0, acc[m][0], 0, 0, 0);
      acc[m][1] = __builtin_amdgcn_mfma_f32_16x16x32_f16(af[m], bf1, acc[m][1], 0, 0, 0);
    }
    __builtin_amdgcn_s_setprio(0);
    // ---- phase B: reads bf2,bf3 | stageB(kt+2) | vmcnt | BAR | MFMA n2,n3
    half8 bf2 = *(const half8*)(buf + oB0 + 2048);
    half8 bf3 = *(const half8*)(buf + oB0 + 3072);
    if (kt + 2 < Ksteps) {
      stageB((kt + 2) % 3, kt + 2);
      asm volatile("s_waitcnt vmcnt(3)" ::: "memory");  // certify slot kt+1
    } else if (kt == Ksteps - 2) {
      asm volatile("s_waitcnt vmcnt(0)" ::: "memory");
    }
    asm volatile("" ::: "memory");
    __builtin_amdgcn_s_barrier();
    asm volatile("s_waitcnt lgkmcnt(0)" ::: "memory");
    __builtin_amdgcn_s_setprio(1);
#pragma unroll
    for (int m = 0; m < 4; ++m) {
      acc[m][2] = __builtin_amdgcn_mfma_f32_16x16x32_f16(af[m], bf2, acc[m][2], 0, 0, 0);
      acc[m][3] = __builtin_amdgcn_mfma_f32_16x16x32_f16(af[m], bf3, acc[m][3], 0, 0, 0);
    }
    __builtin_amdgcn_s_setprio(0);
  }

  __syncthreads();

  // ---- epilogue: per-wave LDS restage (no barriers), bias + stats fused ----
  float* const swv = (float*)smem + wave * 1152;  // 16 x 68 f32 per wave
  float biasv[4];
#pragma unroll
  for (int n = 0; n < 4; ++n) {
    const int c = n0 + wn * 64 + n * 16 + l16;
    biasv[n] = (bias != nullptr && c < Ncols) ? bias[c] : 0.f;
  }
  float cs[4] = {}, cq[4] = {};
  const int rowr = lane >> 2;
  const int colc = (lane & 3) << 4;

#pragma unroll
  for (int m = 0; m < 4; ++m) {
#pragma unroll
    for (int n = 0; n < 4; ++n)
#pragma unroll
      for (int r = 0; r < 4; ++r) {
        const float v = acc[m][n][r] + biasv[n];
        swv[(lg * 4 + r) * 68 + n * 16 + l16] = v;
        if constexpr (EPI == 0) {
          cs[n] += v;
          cq[n] += v * v;
        }
      }
    asm volatile("s_waitcnt lgkmcnt(0)" ::: "memory");  // cross-lane LDS alias
    const float* sp = swv + rowr * 68 + colc;
    const int grow = m0 + wm * 64 + m * 16 + rowr;
    if constexpr (EPI == 2) {
      float* rp = (float*)outp + (size_t)blockIdx.z * oz + (size_t)grow * ldOut;
#pragma unroll
      for (int j = 0; j < 4; ++j) {
        const int c = n0 + wn * 64 + colc + j * 4;
        const f32x4 v = *(const f32x4*)(sp + j * 4);
        if (c + 3 < Ncols) {
          *(f32x4*)(rp + c) = v;
        } else {
#pragma unroll
          for (int e = 0; e < 4; ++e)
            if (c + e < Ncols) rp[c + e] = v[e];
        }
      }
    } else {
      // tiled f16 store (consumer K = 1024): panel 256x1024 = 262144 elems
      const f32x4 v0 = *(const f32x4*)(sp);
      const f32x4 v1 = *(const f32x4*)(sp + 4);
      const f32x4 v2 = *(const f32x4*)(sp + 8);
      const f32x4 v3 = *(const f32x4*)(sp + 12);
      half8 h0, h1;
#pragma unroll
      for (int e = 0; e < 4; ++e) {
        h0[e] = (f16)v0[e];
        h0[4 + e] = (f16)v1[e];
        h1[e] = (f16)v2[e];
        h1[4 + e] = (f16)v3[e];
      }
      f16* o16 = (f16*)outp;
      const size_t dstE = (size_t)(grow >> 8) * 262144 +
                          (size_t)((n0 >> 5) + wn * 2 + (colc >> 5)) * 8192 +
                          (size_t)(grow & 255) * 32 + (colc & 31);
      *(half8*)(o16 + dstE) = h0;
      *(half8*)(o16 + dstE + 8) = h1;
    }
    asm volatile("s_waitcnt lgkmcnt(0)" ::: "memory");  // reads done before rewrite
  }

  if constexpr (EPI == 0) {
    // direct per-(wm,lg) partial row; no cross-lane shuffles.
    float2* pp = partial + ((size_t)(by * 2 + wm) * 4 + lg) * 1024 + n0 + wn * 64 + l16;
#pragma unroll
    for (int n = 0; n < 4; ++n) pp[n * 16] = make_float2(cs[n], cq[n]);
  }
}

// ---------------------------------------------------------------------------
// stage A: each block sums 64 partial rows for 256 cols (fully parallel).
__global__ void bn_red_k(const float2* __restrict__ partial, float2* __restrict__ part2) {
  const int c = blockIdx.x * 256 + threadIdx.x;
  const int chunk = blockIdx.y;
  const float2* p = partial + (size_t)chunk * 64 * 1024 + c;
  float s = 0.f, q = 0.f;
#pragma unroll 4
  for (int i = 0; i < 64; ++i) {
    float2 v = p[(size_t)i * 1024];
    s += v.x;
    q += v.y;
  }
  part2[(size_t)chunk * 1024 + c] = make_float2(s, q);
}

__global__ void bn_fin_k(const float2* __restrict__ part2, int chunkStart, int nchunks,
                         const float* __restrict__ g, const float* __restrict__ beta,
                         f16* __restrict__ scH, f16* __restrict__ shH, float invB) {
  const int c = blockIdx.x * 256 + threadIdx.x;
  float s = 0.f, q = 0.f;
  const float2* p = part2 + (size_t)chunkStart * 1024 + c;
  for (int i = 0; i < nchunks; ++i) {
    float2 v = p[(size_t)i * 1024];
    s += v.x;
    q += v.y;
  }
  float m = s * invB;
  float var = q * invB - m * m;
  float sc = rsqrtf(var + 1e-3f) * g[c];
  scH[c] = (f16)sc;
  shH[c] = (f16)(beta[c] - m * sc);
}

__global__ void bn_fin3_k(const float2* __restrict__ part2, int cps, float invB,
                          const float* __restrict__ g0, const float* __restrict__ b0,
                          f16* __restrict__ so0, f16* __restrict__ sh0,
                          const float* __restrict__ g1, const float* __restrict__ b1,
                          f16* __restrict__ so1, f16* __restrict__ sh1,
                          const float* __restrict__ g2, const float* __restrict__ b2,
                          f16* __restrict__ so2, f16* __restrict__ sh2) {
  const int j = blockIdx.y;
  const float* g = j == 0 ? g0 : (j == 1 ? g1 : g2);
  const float* bt = j == 0 ? b0 : (j == 1 ? b1 : b2);
  f16* so = j == 0 ? so0 : (j == 1 ? so1 : so2);
  f16* sh = j == 0 ? sh0 : (j == 1 ? sh1 : sh2);
  const int c = blockIdx.x * 256 + threadIdx.x;
  float s = 0.f, q = 0.f;
  const float2* p = part2 + (size_t)j * cps * 1024 + c;
  for (int i = 0; i < cps; ++i) {
    float2 v = p[(size_t)i * 1024];
    s += v.x;
    q += v.y;
  }
  float m = s * invB;
  float var = q * invB - m * m;
  float sc = rsqrtf(var + 1e-3f) * g[c];
  so[c] = (f16)sc;
  sh[c] = (f16)(bt[c] - m * sc);
}

// ---------------------------------------------------------------------------
// weights -> padded f16, K-TILED: elem(n,k) at (n>>8)*256*KP + (k>>5)*8192 +
// (n&255)*32 + (k&31)
__global__ void cvt_all_k(const float* __restrict__ Wi1, const float* __restrict__ Wm1,
                          const float* __restrict__ Wi3, const float* __restrict__ Wm2,
                          const float* __restrict__ Wm3, const float* __restrict__ Wm4,
                          f16* __restrict__ Wi1p, f16* __restrict__ Wm1p,
                          f16* __restrict__ Wi3p, f16* __restrict__ Wm2p,
                          f16* __restrict__ Wm3p, f16* __restrict__ Wm4p) {
  const int k = blockIdx.x * 256 + threadIdx.x;
  const int row = blockIdx.y;
  const float* src;
  f16* dst;
  int n, K, KP, Nreal;
  if (row < 2048) {
    KP = 384;
    if (row < 1024) { src = Wi1; dst = Wi1p; n = row; K = 300; Nreal = 1024; }
    else { src = Wm1; dst = Wm1p; n = row - 1024; K = 310; Nreal = 1024; }
  } else {
    KP = 1024;
    if (row < 2560) { src = Wi3; dst = Wi3p; n = row - 2048; K = 1024; Nreal = 300; }
    else if (row < 3584) { src = Wm2; dst = Wm2p; n = row - 2560; K = 1024; Nreal = 1024; }
    else if (row < 4608) { src = Wm3; dst = Wm3p; n = row - 3584; K = 1024; Nreal = 1024; }
    else { src = Wm4; dst = Wm4p; n = row - 4608; K = 1024; Nreal = 300; }
  }
  if (k >= KP) return;
  float v = (n < Nreal && k < K) ? src[(size_t)n * K + k] : 0.f;
  dst[(size_t)(n >> 8) * 256 * KP + (size_t)(k >> 5) * 8192 +
      (size_t)(n & 255) * 32 + (k & 31)] = (f16)v;
}

// Wt[k'][n'] = W[n'][k'], 1024x1024, f32 -> f16, K-tiled output
__global__ void cvt_wT_k(const float* __restrict__ W, f16* __restrict__ Wt) {
  __shared__ f16 tile[64][65];
  const int bx = blockIdx.x * 64, by = blockIdx.y * 64;
  const int tc = threadIdx.x & 63, tr = threadIdx.x >> 6;
#pragma unroll
  for (int r = tr; r < 64; r += 4)
    tile[r][tc] = (f16)W[(size_t)(by + r) * 1024 + bx + tc];
  __syncthreads();
#pragma unroll
  for (int r = tr; r < 64; r += 4) {
    const int nr = bx + r;    // output row (orig col)
    const int kc = by + tc;   // output col (orig row)
    Wt[(size_t)(nr >> 8) * 262144 + (size_t)(kc >> 5) * 8192 +
       (size_t)(nr & 255) * 32 + (kc & 31)] = tile[tc][r];
  }
}

// input pack (f32 -> f16), K-tiled (KP=384): panel 256*384 = 98304 elems
__global__ void cvt_in_k(const float* __restrict__ ip, const float* __restrict__ in_,
                         const float* __restrict__ tg, f16* __restrict__ Ain, int B) {
  const int gid = blockIdx.x * 256 + threadIdx.x;
  const int row = gid / 48;
  const int c0 = (gid - row * 48) * 8;
  if (row >= B) return;
  half8 vp = {}, vn = {}, vm = {};
  const float* rp = ip + (size_t)row * 300;
  const float* rn = in_ + (size_t)row * 300;
  const float* rt = tg + (size_t)row * 300;
#pragma unroll
  for (int e = 0; e < 8; ++e) {
    const int c = c0 + e;
    if (c < 300) {
      vp[e] = (f16)rp[c];
      vn[e] = (f16)rn[c];
    }
    if (c >= 10 && c < 310) vm[e] = (f16)rt[c - 10];
  }
  const size_t o = (size_t)(row >> 8) * 98304 + (size_t)(c0 >> 5) * 8192 +
                   (size_t)(row & 255) * 32 + (c0 & 31);
  const size_t pstr = (size_t)(B >> 8) * 98304;
  *(half8*)(Ain + o) = vp;
  *(half8*)(Ain + pstr + o) = vn;
  *(half8*)(Ain + 2 * pstr + o) = vm;
}

// reduce 8 K-split f32 partials -> f16 Wfold (K-tiled, KP=1024)
__global__ void fold_red_k(const float* __restrict__ pf, f16* __restrict__ Wf) {
  const int i = blockIdx.x * 256 + threadIdx.x;  // 512*1024 elements
  float s = 0.f;
#pragma unroll
  for (int z = 0; z < 8; ++z) s += pf[(size_t)z * 524288 + i];
  const int n = i >> 10, k = i & 1023;
  Wf[(size_t)(n >> 8) * 262144 + (size_t)(k >> 5) * 8192 +
     (size_t)(n & 255) * 32 + (k & 31)] = (f16)s;
}

// bfold[n] = sum_j Wi3p[n][j]*bi2[j] + bi3[n]   (Wi3p is K-tiled, KP=1024)
__global__ void bfold_k(const f16* __restrict__ Wi3p, const float* __restrict__ bi2,
                        const float* __restrict__ bi3, float* __restrict__ bf) {
  const int n = blockIdx.x;
  const int t = threadIdx.x;
  const size_t nb = (size_t)(n >> 8) * 262144 + (size_t)(n & 255) * 32;
  float s = 0.f;
  for (int j = t; j < 1024; j += 256)
    s += (float)Wi3p[nb + (size_t)(j >> 5) * 8192 + (j & 31)] * bi2[j];
#pragma unroll
  for (int off = 32; off; off >>= 1) s += __shfl_xor(s, off);
  __shared__ float red[4];
  if ((t & 63) == 0) red[t >> 6] = s;
  __syncthreads();
  if (t == 0) bf[n] = red[0] + red[1] + red[2] + red[3] + (n < 300 ? bi3[n] : 0.f);
}

// --------------------------- loc branch ------------------------------------
__global__ void loc_stats_k(const float* __restrict__ lat, const float* __restrict__ lon,
                            const float* __restrict__ Wloc, const float* __restrict__ bloc,
                            float* __restrict__ partial) {
  const int t = threadIdx.x;
  const int row = blockIdx.x * 256 + t;
  float la = lat[row], lo = lon[row];
  float s[10], q[10];
#pragma unroll
  for (int j = 0; j < 10; ++j) {
    float y = la * Wloc[j * 2] + lo * Wloc[j * 2 + 1] + bloc[j];
    s[j] = y;
    q[j] = y * y;
  }
#pragma unroll
  for (int j = 0; j < 10; ++j)
    for (int off = 32; off; off >>= 1) {
      s[j] += __shfl_xor(s[j], off);
      q[j] += __shfl_xor(q[j], off);
    }
  __shared__ float red[4][20];
  const int wave = t >> 6, lane = t & 63;
  if (lane == 0) {
#pragma unroll
    for (int j = 0; j < 10; ++j) {
      red[wave][j] = s[j];
      red[wave][10 + j] = q[j];
    }
  }
  __syncthreads();
  if (t < 20) partial[blockIdx.x * 20 + t] = red[0][t] + red[1][t] + red[2][t] + red[3][t];
}

__global__ void loc_fin_k(const float* __restrict__ partial, int nblk,
                          const float* __restrict__ g, const float* __restrict__ beta,
                          float2* __restrict__ ss, float invB) {
  int t = threadIdx.x;
  if (t < 10) {
    float s = 0.f, q = 0.f;
    for (int b = 0; b < nblk; ++b) {
      s += partial[b * 20 + t];
      q += partial[b * 20 + 10 + t];
    }
    float m = s * invB;
    float var = q * invB - m * m;
    float sc = rsqrtf(var + 1e-3f) * g[t];
    ss[t] = make_float2(sc, beta[t] - m * sc);
  }
}

// writes Am cols 0..9 (K-tiled Am, KP=384: ktile 0, so offset is simple)
__global__ void loc_write_k(const float* __restrict__ lat, const float* __restrict__ lon,
                            const float* __restrict__ Wloc, const float* __restrict__ bloc,
                            const float2* __restrict__ ss, f16* __restrict__ Am) {
  const int row = blockIdx.x * 256 + threadIdx.x;
  float la = lat[row], lo = lon[row];
  f16* dst = Am + (size_t)(row >> 8) * 98304 + (size_t)(row & 255) * 32;
#pragma unroll
  for (int j = 0; j < 10; ++j) {
    float y = la * Wloc[j * 2] + lo * Wloc[j * 2 + 1] + bloc[j];
    float2 sv = ss[j];
    dst[j] = (f16)fmaxf(y * sv.x + sv.y, 0.f);
  }
}

// --------------------------- count -----------------------------------------
__global__ void count_k(const float* __restrict__ P, const float* __restrict__ Nn,
                        const float* __restrict__ Aa, int B, int* __restrict__ cnt) {
  const int gw = (blockIdx.x * blockDim.x + threadIdx.x) >> 6;
  const int lane = threadIdx.x & 63;
  const int nw = (gridDim.x * blockDim.x) >> 6;
  int local = 0;
  for (int row = gw; row < B; row += nw) {
    const float* ar = Aa + (size_t)row * 300;
    const float* pr = P + (size_t)row * 300;
    const float* nr = Nn + (size_t)row * 300;
    float sp = 0.f, sn = 0.f;
    for (int e = lane; e < 300; e += 64) {
      float av = ar[e];
      float d1 = av - pr[e] + 1e-6f;
      float d2 = av - nr[e] + 1e-6f;
      sp += d1 * d1;
      sn += d2 * d2;
    }
#pragma unroll
    for (int off = 32; off; off >>= 1) {
      sp += __shfl_xor(sp, off);
      sn += __shfl_xor(sn, off);
    }
    if (lane == 0 && (sqrtf(sn) - sqrtf(sp) > 0.1f)) ++local;
  }
  if (lane == 0 && local) atomicAdd(cnt, local);
}

__global__ void zero_i32(int* p) {
  if (threadIdx.x == 0 && blockIdx.x == 0) *p = 0;
}
__global__ void write_cnt_k(const int* c, float* o) {
  if (threadIdx.x == 0 && blockIdx.x == 0) *o = (float)(*c);
}

// ---------------------------------------------------------------------------
extern "C" void kernel_launch(void* const* d_in, const int* in_sizes, int n_in,
                              void* d_out, int out_size, void* d_ws, size_t ws_size,
                              hipStream_t stream) {
  const float* img_p = (const float*)d_in[0];
  const float* img_n = (const float*)d_in[1];
  const float* tag = (const float*)d_in[2];
  const float* lat = (const float*)d_in[3];
  const float* lon = (const float*)d_in[4];
  const float* Wi1 = (const float*)d_in[5];
  const float* bi1 = (const float*)d_in[6];
  const float* gi1 = (const float*)d_in[7];
  const float* bti1 = (const float*)d_in[8];
  const float* Wi2 = (const float*)d_in[9];
  const float* bi2 = (const float*)d_in[10];
  const float* Wi3 = (const float*)d_in[11];
  const float* bi3 = (const float*)d_in[12];
  const float* Wloc = (const float*)d_in[13];
  const float* bloc = (const float*)d_in[14];
  const float* gloc = (const float*)d_in[15];
  const float* btloc = (const float*)d_in[16];
  const float* Wm1 = (const float*)d_in[17];
  const float* bm1 = (const float*)d_in[18];
  const float* gm1 = (const float*)d_in[19];
  const float* btm1 = (const float*)d_in[20];
  const float* Wm2 = (const float*)d_in[21];
  const float* bm2 = (const float*)d_in[22];
  const float* gm2 = (const float*)d_in[23];
  const float* btm2 = (const float*)d_in[24];
  const float* Wm3 = (const float*)d_in[25];
  const float* bm3 = (const float*)d_in[26];
  const float* gm3 = (const float*)d_in[27];
  const float* btm3 = (const float*)d_in[28];
  const float* Wm4 = (const float*)d_in[29];
  const float* bm4 = (const float*)d_in[30];

  const int B = in_sizes[3];  // 32768
  const int MT = B / 128;     // 256 (BM=128 tile units)
  float* out = (float*)d_out;
  float* outP = out;
  float* outN = out + (size_t)B * 300;
  float* outA = out + (size_t)2 * B * 300;
  float* outC = out + (size_t)3 * B * 300;

  char* w = (char*)d_ws;
  auto alloc = [&](size_t bytes) {
    char* p = w;
    w += (bytes + 255) & ~(size_t)255;
    return p;
  };

  f16* Wi1p = (f16*)alloc((size_t)1024 * 384 * 2);
  f16* Wm1p = (f16*)alloc((size_t)1024 * 384 * 2);
  f16* Wi2T = (f16*)alloc((size_t)1024 * 1024 * 2);
  f16* Wi3p = (f16*)alloc((size_t)512 * 1024 * 2);
  f16* Wm2p = (f16*)alloc((size_t)1024 * 1024 * 2);
  f16* Wm3p = (f16*)alloc((size_t)1024 * 1024 * 2);
  f16* Wm4p = (f16*)alloc((size_t)512 * 1024 * 2);
  f16* Wfold = (f16*)alloc((size_t)512 * 1024 * 2);
  float* bfold = (float*)alloc(512 * 4);
  f16* ssT = (f16*)alloc(10 * 1024 * 2);
  f16 *scP1 = ssT, *shP1 = ssT + 1024, *scN1 = ssT + 2048, *shN1 = ssT + 3072;
  f16 *scM1 = ssT + 4096, *shM1 = ssT + 5120, *scM2 = ssT + 6144, *shM2 = ssT + 7168;
  f16 *scM3 = ssT + 8192, *shM3 = ssT + 9216;
  float* locpart = (float*)alloc((size_t)(B / 256) * 20 * 4);
  float2* locss = (float2*)alloc(16 * 8);
  int* cnt = (int*)alloc(256);
  f16* Ain = (f16*)alloc((size_t)3 * B * 384 * 2);  // [p; n; m], K-tiled
  f16* Am = Ain + (size_t)2 * B * 384;
  f16* ACT0 = (f16*)alloc((size_t)3 * B * 1024 * 2);  // S1 out (K-tiled)
  f16* ACT0m = ACT0 + (size_t)2 * B * 1024;
  f16* ACT1m = (f16*)alloc((size_t)B * 1024 * 2);     // mm ping/pong (K-tiled)
  float2* part = (float2*)alloc((size_t)6144 * 1024 * 8);  // stats partials
  float* partF = (float*)part;  // fold K-split partials alias (16MB < 50MB)
  float2* part2 = (float2*)alloc((size_t)96 * 1024 * 8);   // stage-2 partials
  (void)ws_size;
  (void)out_size;
  (void)n_in;

  const float invB = 1.f / (float)B;
  const int BIG = 1 << 30;

  // weight + input conversion (all K-tiled)
  cvt_all_k<<<dim3(4, 5120), 256, 0, stream>>>(Wi1, Wm1, Wi3, Wm2, Wm3, Wm4,
                                               Wi1p, Wm1p, Wi3p, Wm2p, Wm3p, Wm4p);
  cvt_wT_k<<<dim3(16, 16), 256, 0, stream>>>(Wi2, Wi2T);
  cvt_in_k<<<dim3(B * 48 / 256), 256, 0, stream>>>(img_p, img_n, tag, Ain, B);

  // loc branch (fills Am cols 0..9)
  loc_stats_k<<<dim3(B / 256), 256, 0, stream>>>(lat, lon, Wloc, bloc, locpart);
  loc_fin_k<<<dim3(1), 64, 0, stream>>>(locpart, B / 256, gloc, btloc, locss, invB);
  loc_write_k<<<dim3(B / 256), 256, 0, stream>>>(lat, lon, Wloc, bloc, locss, Am);

  // weight fold: Wfold = Wi3 @ Wi2, split-K over z (128 wgs), then reduce
  bfold_k<<<dim3(512), 256, 0, stream>>>(Wi3p, bi2, bi3, bfold);
  gemm128_k<2, 0><<<dim3(4, 4, 8), 512, 0, stream>>>(
      Wi3p, 4, 1024, partF, 1024, 1024, nullptr, BIG, 32768, 524288,
      Wi2T, nullptr, nullptr, nullptr, Wi2T, nullptr, nullptr, nullptr);
  fold_red_k<<<dim3(2048), 256, 0, stream>>>(partF, Wfold);

  // S1 on [p;n;m] in ONE grouped dispatch (M=3B, K=384): by<2MT -> Wi1, else Wm1
  gemm128_k<0, 0><<<dim3(4, 3 * MT), 512, 0, stream>>>(
      Ain, 12, 384, ACT0, 1024, 1024, part, 2 * MT, 0, 0,
      Wi1p, bi1, nullptr, nullptr, Wm1p, bm1, nullptr, nullptr);
  // stats: 6144 partial rows -> 96 chunk rows -> 3 (sc,sh) sets (32 chunks ea)
  bn_red_k<<<dim3(4, 96), 256, 0, stream>>>(part, part2);
  bn_fin3_k<<<dim3(4, 3), 256, 0, stream>>>(
      part2, 32, invB,
      gi1, bti1, scP1, shP1, gi1, bti1, scN1, shN1, gm1, btm1, scM1, shM1);

  // folded img layers 2+3: BN+ReLU fused on A, grouped per branch-half -> d_out
  gemm128_k<2, 1><<<dim3(2, 2 * MT), 512, 0, stream>>>(
      ACT0, 32, 1024, outP, 300, 300, part, MT, 0, 0,
      Wfold, bfold, scP1, shP1, Wfold, bfold, scN1, shN1);

  // mm branch
  gemm128_k<0, 1><<<dim3(4, MT), 512, 0, stream>>>(
      ACT0m, 32, 1024, ACT1m, 1024, 1024, part, BIG, 0, 0,
      Wm2p, bm2, scM1, shM1, Wm2p, bm2, scM1, shM1);
  bn_red_k<<<dim3(4, 32), 256, 0, stream>>>(part, part2);
  bn_fin_k<<<dim3(4), 256, 0, stream>>>(part2, 0, 32, gm2, btm2, scM2, shM2, invB);
  gemm128_k<0, 1><<<dim3(4, MT), 512, 0, stream>>>(
      ACT1m, 32, 1024, ACT0, 1024, 1024, part, BIG, 0, 0,
      Wm3p, bm3, scM2, shM2, Wm3p, bm3, scM2, shM2);
  bn_red_k<<<dim3(4, 32), 256, 0, stream>>>(part, part2);
  bn_fin_k<<<dim3(4), 256, 0, stream>>>(part2, 0, 32, gm3, btm3, scM3, shM3, invB);
  gemm128_k<2, 1><<<dim3(2, MT), 512, 0, stream>>>(
      ACT0, 32, 1024, outA, 300, 300, part, BIG, 0, 0,
      Wm4p, bm4, scM3, shM3, Wm4p, bm4, scM3, shM3);

  // pairwise distances + margin count
  zero_i32<<<1, 64, 0, stream>>>(cnt);
  count_k<<<dim3(1024), 256, 0, stream>>>(outP, outN, outA, B, cnt);
  write_cnt_k<<<1, 64, 0, stream>>>(cnt, outC);
}

// Round 15
// 676.718 us; speedup vs baseline: 1.0639x; 1.0639x over previous
//
#include <hip/hip_runtime.h>

typedef _Float16 f16;
typedef _Float16 half8 __attribute__((ext_vector_type(8)));
typedef float f32x4 __attribute__((ext_vector_type(4)));

__device__ __forceinline__ void gl_lds16(const void* g, void* l) {
  __builtin_amdgcn_global_load_lds(
      (__attribute__((address_space(1))) void*)(size_t)g,
      (__attribute__((address_space(3))) void*)l, 16, 0, 0);
}

// ---------------------------------------------------------------------------
// 128x256 GEMM, 2 blocks/CU (76KB LDS, VGPR 56 @ __launch_bounds__(512,4)).
// Ring-3 x 24KB slots, r12-proven 2-phase counted-vmcnt schedule (see r14).
// r15 change: EPI0 stats are reduced IN-BLOCK via LDS to ONE partial row per
// block (r14: 8 rows/block -> S1 wrote 50MB of partials; write stream is the
// measured bottleneck: WRITE 245MB @ ~2.0 TB/s vs FETCH 45MB).
// K-TILED operands: elem(m,k) at (m>>8)*256*KP + (k>>5)*8192 + (m&255)*32 +
// (k&31).  EPI 0/1: f16 out K-tiled (+EPI0 stats).  EPI 2: f32 row-major.
// BNA 1: fused BatchNorm+ReLU from LDS tables.  Ksteps >= 3.
// ---------------------------------------------------------------------------
template <int EPI, int BNA>
__global__ __launch_bounds__(512, 4) void gemm128_k(
    const f16* __restrict__ A, int Ksteps, int KP,
    void* __restrict__ outp, int ldOut, int Ncols,
    float2* __restrict__ partial, int r1, int kz, int oz,
    const f16* __restrict__ B0, const float* __restrict__ bias0,
    const f16* __restrict__ sc0, const f16* __restrict__ sh0,
    const f16* __restrict__ B1, const float* __restrict__ bias1,
    const f16* __restrict__ sc1, const f16* __restrict__ sh1) {
  __shared__ char smem[77824];  // 3 x 24KB slots + 2x2KB BN tables

  const int t = threadIdx.x;
  const int lane = t & 63;
  const int wave = t >> 6;
  const int wm = wave >> 2, wn = wave & 3;  // 2M x 4N, per-wave 64x64
  const int l16 = lane & 15, lg = lane >> 4;

  // bijective XCD-chunked swizzle (x*y grids here have nwg % 8 == 0)
  int bx = blockIdx.x, by = blockIdx.y;
  {
    const int nwg = gridDim.x * gridDim.y;
    const int wg = bx + gridDim.x * by;
    const int cpx = nwg >> 3;
    const int newid = (wg & 7) * cpx + (wg >> 3);
    bx = newid % gridDim.x;
    by = newid / gridDim.x;
  }
  const int m0 = by * 128;
  const int n0 = bx * 256;

  const f16* Bw = (by >= r1) ? B1 : B0;
  const float* bias = (by >= r1) ? bias1 : bias0;
  const f16* scH = (by >= r1) ? sc1 : sc0;
  const f16* shH = (by >= r1) ? sh1 : sh0;

  f32x4 acc[4][4] = {};

  const int rA = t >> 2;
  const int g16 = ((t & 3) ^ ((t >> 3) & 3)) * 16;
  const f16* Apan = A + (size_t)(m0 >> 8) * 256 * KP + (size_t)blockIdx.z * kz;
  const f16* Bpan = Bw + (size_t)(n0 >> 8) * 256 * KP + (size_t)blockIdx.z * kz;
  const char* gA = (const char*)Apan + (m0 & 255) * 64 + rA * 64 + g16;
  const char* gB = (const char*)Bpan + rA * 64 + g16;

  auto stageA = [&](int slot, int kt) {  // 8KB: 1 gl_lds per thread
    gl_lds16(gA + (size_t)kt * 16384, smem + slot * 24576 + t * 16);
  };
  auto stageB = [&](int slot, int kt) {  // 16KB: 2 gl_lds per thread
    const char* p = gB + (size_t)kt * 16384;
    char* d = smem + slot * 24576 + 8192 + t * 16;
    gl_lds16(p, d);
    gl_lds16(p + 8192, d + 8192);
  };

  // ---- prologue: BN table FIRST (skew retires in vmcnt), then slots 0..2
  if constexpr (BNA) {
    if (t < 128)
      gl_lds16((const char*)scH + t * 16, smem + 73728 + t * 16);
    else if (t < 256)
      gl_lds16((const char*)shH + (t - 128) * 16, smem + 75776 + (t - 128) * 16);
  }
  stageA(0, 0);
  stageB(0, 0);
  stageA(1, 1);
  stageB(1, 1);
  stageA(2, 2);
  stageB(2, 2);
  asm volatile("s_waitcnt vmcnt(6)" ::: "memory");  // slot0 (+table) landed
  __builtin_amdgcn_s_barrier();
  asm volatile("" ::: "memory");

  // per-lane constant LDS fragment bases
  const int xsw = (lg ^ ((l16 >> 1) & 3)) << 4;
  const int oA0 = (wm * 64 + l16) * 64 + xsw;          // + m*1024
  const int oB0 = 8192 + (wn * 64 + l16) * 64 + xsw;   // + n*1024

  for (int kt = 0; kt < Ksteps; ++kt) {
    const int slot = kt % 3;
    const char* buf = smem + slot * 24576;
    // ---- phase A: reads | stageA(kt+2) | BAR | lgkm0 | BNA | MFMA n0,n1
    half8 af[4], bf0, bf1, scv, shv;
#pragma unroll
    for (int m = 0; m < 4; ++m) af[m] = *(const half8*)(buf + oA0 + m * 1024);
    bf0 = *(const half8*)(buf + oB0);
    bf1 = *(const half8*)(buf + oB0 + 1024);
    if constexpr (BNA) {
      scv = *(const half8*)(smem + 73728 + kt * 64 + lg * 16);
      shv = *(const half8*)(smem + 75776 + kt * 64 + lg * 16);
    }
    if (kt + 2 < Ksteps) stageA((kt + 2) % 3, kt + 2);
    asm volatile("" ::: "memory");
    __builtin_amdgcn_s_barrier();
    asm volatile("s_waitcnt lgkmcnt(0)" ::: "memory");
    if constexpr (BNA) {
      const half8 zeroh = {};
#pragma unroll
      for (int m = 0; m < 4; ++m)
        af[m] = __builtin_elementwise_max((half8)(af[m] * scv + shv), zeroh);
    }
    __builtin_amdgcn_s_setprio(1);
#pragma unroll
    for (int m = 0; m < 4; ++m) {
      acc[m][0] = __builtin_amdgcn_mfma_f32_16x16x32_f16(af[m], bf0, acc[m][0], 0, 0, 0);
      acc[m][1] = __builtin_amdgcn_mfma_f32_16x16x32_f16(af[m], bf1, acc[m][1], 0, 0, 0);
    }
    __builtin_amdgcn_s_setprio(0);
    // ---- phase B: reads bf2,bf3 | stageB(kt+2) | vmcnt | BAR | MFMA n2,n3
    half8 bf2 = *(const half8*)(buf + oB0 + 2048);
    half8 bf3 = *(const half8*)(buf + oB0 + 3072);
    if (kt + 2 < Ksteps) {
      stageB((kt + 2) % 3, kt + 2);
      asm volatile("s_waitcnt vmcnt(3)" ::: "memory");  // certify slot kt+1
    } else if (kt == Ksteps - 2) {
      asm volatile("s_waitcnt vmcnt(0)" ::: "memory");
    }
    asm volatile("" ::: "memory");
    __builtin_amdgcn_s_barrier();
    asm volatile("s_waitcnt lgkmcnt(0)" ::: "memory");
    __builtin_amdgcn_s_setprio(1);
#pragma unroll
    for (int m = 0; m < 4; ++m) {
      acc[m][2] = __builtin_amdgcn_mfma_f32_16x16x32_f16(af[m], bf2, acc[m][2], 0, 0, 0);
      acc[m][3] = __builtin_amdgcn_mfma_f32_16x16x32_f16(af[m], bf3, acc[m][3], 0, 0, 0);
    }
    __builtin_amdgcn_s_setprio(0);
  }

  __syncthreads();

  // ---- epilogue: per-wave LDS restage (no barriers), bias + stats fused ----
  float* const swv = (float*)smem + wave * 1152;  // 16 x 68 f32 per wave
  float biasv[4];
#pragma unroll
  for (int n = 0; n < 4; ++n) {
    const int c = n0 + wn * 64 + n * 16 + l16;
    biasv[n] = (bias != nullptr && c < Ncols) ? bias[c] : 0.f;
  }
  float cs[4] = {}, cq[4] = {};
  const int rowr = lane >> 2;
  const int colc = (lane & 3) << 4;

#pragma unroll
  for (int m = 0; m < 4; ++m) {
#pragma unroll
    for (int n = 0; n < 4; ++n)
#pragma unroll
      for (int r = 0; r < 4; ++r) {
        const float v = acc[m][n][r] + biasv[n];
        swv[(lg * 4 + r) * 68 + n * 16 + l16] = v;
        if constexpr (EPI == 0) {
          cs[n] += v;
          cq[n] += v * v;
        }
      }
    asm volatile("s_waitcnt lgkmcnt(0)" ::: "memory");  // cross-lane LDS alias
    const float* sp = swv + rowr * 68 + colc;
    const int grow = m0 + wm * 64 + m * 16 + rowr;
    if constexpr (EPI == 2) {
      float* rp = (float*)outp + (size_t)blockIdx.z * oz + (size_t)grow * ldOut;
#pragma unroll
      for (int j = 0; j < 4; ++j) {
        const int c = n0 + wn * 64 + colc + j * 4;
        const f32x4 v = *(const f32x4*)(sp + j * 4);
        if (c + 3 < Ncols) {
          *(f32x4*)(rp + c) = v;
        } else {
#pragma unroll
          for (int e = 0; e < 4; ++e)
            if (c + e < Ncols) rp[c + e] = v[e];
        }
      }
    } else {
      // tiled f16 store (consumer K = 1024): panel 256x1024 = 262144 elems
      const f32x4 v0 = *(const f32x4*)(sp);
      const f32x4 v1 = *(const f32x4*)(sp + 4);
      const f32x4 v2 = *(const f32x4*)(sp + 8);
      const f32x4 v3 = *(const f32x4*)(sp + 12);
      half8 h0, h1;
#pragma unroll
      for (int e = 0; e < 4; ++e) {
        h0[e] = (f16)v0[e];
        h0[4 + e] = (f16)v1[e];
        h1[e] = (f16)v2[e];
        h1[4 + e] = (f16)v3[e];
      }
      f16* o16 = (f16*)outp;
      const size_t dstE = (size_t)(grow >> 8) * 262144 +
                          (size_t)((n0 >> 5) + wn * 2 + (colc >> 5)) * 8192 +
                          (size_t)(grow & 255) * 32 + (colc & 31);
      *(half8*)(o16 + dstE) = h0;
      *(half8*)(o16 + dstE + 8) = h1;
    }
    asm volatile("s_waitcnt lgkmcnt(0)" ::: "memory");  // reads done before rewrite
  }

  if constexpr (EPI == 0) {
    // in-block stats reduction: 8 (wm,lg) row-groups x 256 cols via LDS,
    // then ONE partial row per block (r14 wrote 8 -> 50MB partial traffic).
    __syncthreads();  // all waves done with swv
    float2* arr = (float2*)smem;  // 8 x 256 float2 = 16KB (reuse slot space)
    float2* myrow = arr + (wm * 4 + lg) * 256;
#pragma unroll
    for (int n = 0; n < 4; ++n)
      myrow[wn * 64 + n * 16 + l16] = make_float2(cs[n], cq[n]);
    __syncthreads();
    if (t < 256) {
      float s = 0.f, q = 0.f;
#pragma unroll
      for (int g = 0; g < 8; ++g) {
        const float2 v = arr[g * 256 + t];
        s += v.x;
        q += v.y;
      }
      partial[(size_t)by * 1024 + bx * 256 + t] = make_float2(s, q);
    }
  }
}

// ---------------------------------------------------------------------------
// stage A: each block sums 64 partial rows for 256 cols (fully parallel).
__global__ void bn_red_k(const float2* __restrict__ partial, float2* __restrict__ part2) {
  const int c = blockIdx.x * 256 + threadIdx.x;
  const int chunk = blockIdx.y;
  const float2* p = partial + (size_t)chunk * 64 * 1024 + c;
  float s = 0.f, q = 0.f;
#pragma unroll 4
  for (int i = 0; i < 64; ++i) {
    float2 v = p[(size_t)i * 1024];
    s += v.x;
    q += v.y;
  }
  part2[(size_t)chunk * 1024 + c] = make_float2(s, q);
}

__global__ void bn_fin_k(const float2* __restrict__ part2, int chunkStart, int nchunks,
                         const float* __restrict__ g, const float* __restrict__ beta,
                         f16* __restrict__ scH, f16* __restrict__ shH, float invB) {
  const int c = blockIdx.x * 256 + threadIdx.x;
  float s = 0.f, q = 0.f;
  const float2* p = part2 + (size_t)chunkStart * 1024 + c;
  for (int i = 0; i < nchunks; ++i) {
    float2 v = p[(size_t)i * 1024];
    s += v.x;
    q += v.y;
  }
  float m = s * invB;
  float var = q * invB - m * m;
  float sc = rsqrtf(var + 1e-3f) * g[c];
  scH[c] = (f16)sc;
  shH[c] = (f16)(beta[c] - m * sc);
}

__global__ void bn_fin3_k(const float2* __restrict__ part2, int cps, float invB,
                          const float* __restrict__ g0, const float* __restrict__ b0,
                          f16* __restrict__ so0, f16* __restrict__ sh0,
                          const float* __restrict__ g1, const float* __restrict__ b1,
                          f16* __restrict__ so1, f16* __restrict__ sh1,
                          const float* __restrict__ g2, const float* __restrict__ b2,
                          f16* __restrict__ so2, f16* __restrict__ sh2) {
  const int j = blockIdx.y;
  const float* g = j == 0 ? g0 : (j == 1 ? g1 : g2);
  const float* bt = j == 0 ? b0 : (j == 1 ? b1 : b2);
  f16* so = j == 0 ? so0 : (j == 1 ? so1 : so2);
  f16* sh = j == 0 ? sh0 : (j == 1 ? sh1 : sh2);
  const int c = blockIdx.x * 256 + threadIdx.x;
  float s = 0.f, q = 0.f;
  const float2* p = part2 + (size_t)j * cps * 1024 + c;
  for (int i = 0; i < cps; ++i) {
    float2 v = p[(size_t)i * 1024];
    s += v.x;
    q += v.y;
  }
  float m = s * invB;
  float var = q * invB - m * m;
  float sc = rsqrtf(var + 1e-3f) * g[c];
  so[c] = (f16)sc;
  sh[c] = (f16)(bt[c] - m * sc);
}

// ---------------------------------------------------------------------------
// weights -> padded f16, K-TILED
__global__ void cvt_all_k(const float* __restrict__ Wi1, const float* __restrict__ Wm1,
                          const float* __restrict__ Wi3, const float* __restrict__ Wm2,
                          const float* __restrict__ Wm3, const float* __restrict__ Wm4,
                          f16* __restrict__ Wi1p, f16* __restrict__ Wm1p,
                          f16* __restrict__ Wi3p, f16* __restrict__ Wm2p,
                          f16* __restrict__ Wm3p, f16* __restrict__ Wm4p) {
  const int k = blockIdx.x * 256 + threadIdx.x;
  const int row = blockIdx.y;
  const float* src;
  f16* dst;
  int n, K, KP, Nreal;
  if (row < 2048) {
    KP = 384;
    if (row < 1024) { src = Wi1; dst = Wi1p; n = row; K = 300; Nreal = 1024; }
    else { src = Wm1; dst = Wm1p; n = row - 1024; K = 310; Nreal = 1024; }
  } else {
    KP = 1024;
    if (row < 2560) { src = Wi3; dst = Wi3p; n = row - 2048; K = 1024; Nreal = 300; }
    else if (row < 3584) { src = Wm2; dst = Wm2p; n = row - 2560; K = 1024; Nreal = 1024; }
    else if (row < 4608) { src = Wm3; dst = Wm3p; n = row - 3584; K = 1024; Nreal = 1024; }
    else { src = Wm4; dst = Wm4p; n = row - 4608; K = 1024; Nreal = 300; }
  }
  if (k >= KP) return;
  float v = (n < Nreal && k < K) ? src[(size_t)n * K + k] : 0.f;
  dst[(size_t)(n >> 8) * 256 * KP + (size_t)(k >> 5) * 8192 +
      (size_t)(n & 255) * 32 + (k & 31)] = (f16)v;
}

// Wt[k'][n'] = W[n'][k'], 1024x1024, f32 -> f16, K-tiled output
__global__ void cvt_wT_k(const float* __restrict__ W, f16* __restrict__ Wt) {
  __shared__ f16 tile[64][65];
  const int bx = blockIdx.x * 64, by = blockIdx.y * 64;
  const int tc = threadIdx.x & 63, tr = threadIdx.x >> 6;
#pragma unroll
  for (int r = tr; r < 64; r += 4)
    tile[r][tc] = (f16)W[(size_t)(by + r) * 1024 + bx + tc];
  __syncthreads();
#pragma unroll
  for (int r = tr; r < 64; r += 4) {
    const int nr = bx + r;
    const int kc = by + tc;
    Wt[(size_t)(nr >> 8) * 262144 + (size_t)(kc >> 5) * 8192 +
       (size_t)(nr & 255) * 32 + (kc & 31)] = tile[tc][r];
  }
}

// input pack (f32 -> f16), K-tiled (KP=384): panel 256*384 = 98304 elems
__global__ void cvt_in_k(const float* __restrict__ ip, const float* __restrict__ in_,
                         const float* __restrict__ tg, f16* __restrict__ Ain, int B) {
  const int gid = blockIdx.x * 256 + threadIdx.x;
  const int row = gid / 48;
  const int c0 = (gid - row * 48) * 8;
  if (row >= B) return;
  half8 vp = {}, vn = {}, vm = {};
  const float* rp = ip + (size_t)row * 300;
  const float* rn = in_ + (size_t)row * 300;
  const float* rt = tg + (size_t)row * 300;
#pragma unroll
  for (int e = 0; e < 8; ++e) {
    const int c = c0 + e;
    if (c < 300) {
      vp[e] = (f16)rp[c];
      vn[e] = (f16)rn[c];
    }
    if (c >= 10 && c < 310) vm[e] = (f16)rt[c - 10];
  }
  const size_t o = (size_t)(row >> 8) * 98304 + (size_t)(c0 >> 5) * 8192 +
                   (size_t)(row & 255) * 32 + (c0 & 31);
  const size_t pstr = (size_t)(B >> 8) * 98304;
  *(half8*)(Ain + o) = vp;
  *(half8*)(Ain + pstr + o) = vn;
  *(half8*)(Ain + 2 * pstr + o) = vm;
}

// reduce 8 K-split f32 partials -> f16 Wfold (K-tiled, KP=1024)
__global__ void fold_red_k(const float* __restrict__ pf, f16* __restrict__ Wf) {
  const int i = blockIdx.x * 256 + threadIdx.x;
  float s = 0.f;
#pragma unroll
  for (int z = 0; z < 8; ++z) s += pf[(size_t)z * 524288 + i];
  const int n = i >> 10, k = i & 1023;
  Wf[(size_t)(n >> 8) * 262144 + (size_t)(k >> 5) * 8192 +
     (size_t)(n & 255) * 32 + (k & 31)] = (f16)s;
}

// bfold[n] = sum_j Wi3p[n][j]*bi2[j] + bi3[n]   (Wi3p is K-tiled, KP=1024)
__global__ void bfold_k(const f16* __restrict__ Wi3p, const float* __restrict__ bi2,
                        const float* __restrict__ bi3, float* __restrict__ bf) {
  const int n = blockIdx.x;
  const int t = threadIdx.x;
  const size_t nb = (size_t)(n >> 8) * 262144 + (size_t)(n & 255) * 32;
  float s = 0.f;
  for (int j = t; j < 1024; j += 256)
    s += (float)Wi3p[nb + (size_t)(j >> 5) * 8192 + (j & 31)] * bi2[j];
#pragma unroll
  for (int off = 32; off; off >>= 1) s += __shfl_xor(s, off);
  __shared__ float red[4];
  if ((t & 63) == 0) red[t >> 6] = s;
  __syncthreads();
  if (t == 0) bf[n] = red[0] + red[1] + red[2] + red[3] + (n < 300 ? bi3[n] : 0.f);
}

// --------------------------- loc branch ------------------------------------
__global__ void loc_stats_k(const float* __restrict__ lat, const float* __restrict__ lon,
                            const float* __restrict__ Wloc, const float* __restrict__ bloc,
                            float* __restrict__ partial) {
  const int t = threadIdx.x;
  const int row = blockIdx.x * 256 + t;
  float la = lat[row], lo = lon[row];
  float s[10], q[10];
#pragma unroll
  for (int j = 0; j < 10; ++j) {
    float y = la * Wloc[j * 2] + lo * Wloc[j * 2 + 1] + bloc[j];
    s[j] = y;
    q[j] = y * y;
  }
#pragma unroll
  for (int j = 0; j < 10; ++j)
    for (int off = 32; off; off >>= 1) {
      s[j] += __shfl_xor(s[j], off);
      q[j] += __shfl_xor(q[j], off);
    }
  __shared__ float red[4][20];
  const int wave = t >> 6, lane = t & 63;
  if (lane == 0) {
#pragma unroll
    for (int j = 0; j < 10; ++j) {
      red[wave][j] = s[j];
      red[wave][10 + j] = q[j];
    }
  }
  __syncthreads();
  if (t < 20) partial[blockIdx.x * 20 + t] = red[0][t] + red[1][t] + red[2][t] + red[3][t];
}

__global__ void loc_fin_k(const float* __restrict__ partial, int nblk,
                          const float* __restrict__ g, const float* __restrict__ beta,
                          float2* __restrict__ ss, float invB) {
  int t = threadIdx.x;
  if (t < 10) {
    float s = 0.f, q = 0.f;
    for (int b = 0; b < nblk; ++b) {
      s += partial[b * 20 + t];
      q += partial[b * 20 + 10 + t];
    }
    float m = s * invB;
    float var = q * invB - m * m;
    float sc = rsqrtf(var + 1e-3f) * g[t];
    ss[t] = make_float2(sc, beta[t] - m * sc);
  }
}

// writes Am cols 0..9 (K-tiled Am, KP=384: ktile 0, so offset is simple)
__global__ void loc_write_k(const float* __restrict__ lat, const float* __restrict__ lon,
                            const float* __restrict__ Wloc, const float* __restrict__ bloc,
                            const float2* __restrict__ ss, f16* __restrict__ Am) {
  const int row = blockIdx.x * 256 + threadIdx.x;
  float la = lat[row], lo = lon[row];
  f16* dst = Am + (size_t)(row >> 8) * 98304 + (size_t)(row & 255) * 32;
#pragma unroll
  for (int j = 0; j < 10; ++j) {
    float y = la * Wloc[j * 2] + lo * Wloc[j * 2 + 1] + bloc[j];
    float2 sv = ss[j];
    dst[j] = (f16)fmaxf(y * sv.x + sv.y, 0.f);
  }
}

// --------------------------- count -----------------------------------------
__global__ void count_k(const float* __restrict__ P, const float* __restrict__ Nn,
                        const float* __restrict__ Aa, int B, int* __restrict__ cnt) {
  const int gw = (blockIdx.x * blockDim.x + threadIdx.x) >> 6;
  const int lane = threadIdx.x & 63;
  const int nw = (gridDim.x * blockDim.x) >> 6;
  int local = 0;
  for (int row = gw; row < B; row += nw) {
    const float* ar = Aa + (size_t)row * 300;
    const float* pr = P + (size_t)row * 300;
    const float* nr = Nn + (size_t)row * 300;
    float sp = 0.f, sn = 0.f;
    for (int e = lane; e < 300; e += 64) {
      float av = ar[e];
      float d1 = av - pr[e] + 1e-6f;
      float d2 = av - nr[e] + 1e-6f;
      sp += d1 * d1;
      sn += d2 * d2;
    }
#pragma unroll
    for (int off = 32; off; off >>= 1) {
      sp += __shfl_xor(sp, off);
      sn += __shfl_xor(sn, off);
    }
    if (lane == 0 && (sqrtf(sn) - sqrtf(sp) > 0.1f)) ++local;
  }
  if (lane == 0 && local) atomicAdd(cnt, local);
}

__global__ void zero_i32(int* p) {
  if (threadIdx.x == 0 && blockIdx.x == 0) *p = 0;
}
__global__ void write_cnt_k(const int* c, float* o) {
  if (threadIdx.x == 0 && blockIdx.x == 0) *o = (float)(*c);
}

// ---------------------------------------------------------------------------
extern "C" void kernel_launch(void* const* d_in, const int* in_sizes, int n_in,
                              void* d_out, int out_size, void* d_ws, size_t ws_size,
                              hipStream_t stream) {
  const float* img_p = (const float*)d_in[0];
  const float* img_n = (const float*)d_in[1];
  const float* tag = (const float*)d_in[2];
  const float* lat = (const float*)d_in[3];
  const float* lon = (const float*)d_in[4];
  const float* Wi1 = (const float*)d_in[5];
  const float* bi1 = (const float*)d_in[6];
  const float* gi1 = (const float*)d_in[7];
  const float* bti1 = (const float*)d_in[8];
  const float* Wi2 = (const float*)d_in[9];
  const float* bi2 = (const float*)d_in[10];
  const float* Wi3 = (const float*)d_in[11];
  const float* bi3 = (const float*)d_in[12];
  const float* Wloc = (const float*)d_in[13];
  const float* bloc = (const float*)d_in[14];
  const float* gloc = (const float*)d_in[15];
  const float* btloc = (const float*)d_in[16];
  const float* Wm1 = (const float*)d_in[17];
  const float* bm1 = (const float*)d_in[18];
  const float* gm1 = (const float*)d_in[19];
  const float* btm1 = (const float*)d_in[20];
  const float* Wm2 = (const float*)d_in[21];
  const float* bm2 = (const float*)d_in[22];
  const float* gm2 = (const float*)d_in[23];
  const float* btm2 = (const float*)d_in[24];
  const float* Wm3 = (const float*)d_in[25];
  const float* bm3 = (const float*)d_in[26];
  const float* gm3 = (const float*)d_in[27];
  const float* btm3 = (const float*)d_in[28];
  const float* Wm4 = (const float*)d_in[29];
  const float* bm4 = (const float*)d_in[30];

  const int B = in_sizes[3];  // 32768
  const int MT = B / 128;     // 256 (BM=128 tile units)
  float* out = (float*)d_out;
  float* outP = out;
  float* outN = out + (size_t)B * 300;
  float* outA = out + (size_t)2 * B * 300;
  float* outC = out + (size_t)3 * B * 300;

  char* w = (char*)d_ws;
  auto alloc = [&](size_t bytes) {
    char* p = w;
    w += (bytes + 255) & ~(size_t)255;
    return p;
  };

  f16* Wi1p = (f16*)alloc((size_t)1024 * 384 * 2);
  f16* Wm1p = (f16*)alloc((size_t)1024 * 384 * 2);
  f16* Wi2T = (f16*)alloc((size_t)1024 * 1024 * 2);
  f16* Wi3p = (f16*)alloc((size_t)512 * 1024 * 2);
  f16* Wm2p = (f16*)alloc((size_t)1024 * 1024 * 2);
  f16* Wm3p = (f16*)alloc((size_t)1024 * 1024 * 2);
  f16* Wm4p = (f16*)alloc((size_t)512 * 1024 * 2);
  f16* Wfold = (f16*)alloc((size_t)512 * 1024 * 2);
  float* bfold = (float*)alloc(512 * 4);
  f16* ssT = (f16*)alloc(10 * 1024 * 2);
  f16 *scP1 = ssT, *shP1 = ssT + 1024, *scN1 = ssT + 2048, *shN1 = ssT + 3072;
  f16 *scM1 = ssT + 4096, *shM1 = ssT + 5120, *scM2 = ssT + 6144, *shM2 = ssT + 7168;
  f16 *scM3 = ssT + 8192, *shM3 = ssT + 9216;
  float* locpart = (float*)alloc((size_t)(B / 256) * 20 * 4);
  float2* locss = (float2*)alloc(16 * 8);
  int* cnt = (int*)alloc(256);
  f16* Ain = (f16*)alloc((size_t)3 * B * 384 * 2);  // [p; n; m], K-tiled
  f16* Am = Ain + (size_t)2 * B * 384;
  f16* ACT0 = (f16*)alloc((size_t)3 * B * 1024 * 2);  // S1 out (K-tiled)
  f16* ACT0m = ACT0 + (size_t)2 * B * 1024;
  f16* ACT1m = (f16*)alloc((size_t)B * 1024 * 2);     // mm ping/pong (K-tiled)
  float2* part = (float2*)alloc((size_t)2048 * 1024 * 8);  // partials (covers partF)
  float* partF = (float*)part;  // fold K-split partials alias (16.8MB <= 16.8MB)
  float2* part2 = (float2*)alloc((size_t)16 * 1024 * 8);   // stage-2 partials
  (void)ws_size;
  (void)out_size;
  (void)n_in;

  const float invB = 1.f / (float)B;
  const int BIG = 1 << 30;

  // weight + input conversion (all K-tiled)
  cvt_all_k<<<dim3(4, 5120), 256, 0, stream>>>(Wi1, Wm1, Wi3, Wm2, Wm3, Wm4,
                                               Wi1p, Wm1p, Wi3p, Wm2p, Wm3p, Wm4p);
  cvt_wT_k<<<dim3(16, 16), 256, 0, stream>>>(Wi2, Wi2T);
  cvt_in_k<<<dim3(B * 48 / 256), 256, 0, stream>>>(img_p, img_n, tag, Ain, B);

  // loc branch (fills Am cols 0..9)
  loc_stats_k<<<dim3(B / 256), 256, 0, stream>>>(lat, lon, Wloc, bloc, locpart);
  loc_fin_k<<<dim3(1), 64, 0, stream>>>(locpart, B / 256, gloc, btloc, locss, invB);
  loc_write_k<<<dim3(B / 256), 256, 0, stream>>>(lat, lon, Wloc, bloc, locss, Am);

  // weight fold: Wfold = Wi3 @ Wi2, split-K over z (128 wgs), then reduce
  bfold_k<<<dim3(512), 256, 0, stream>>>(Wi3p, bi2, bi3, bfold);
  gemm128_k<2, 0><<<dim3(4, 4, 8), 512, 0, stream>>>(
      Wi3p, 4, 1024, partF, 1024, 1024, nullptr, BIG, 32768, 524288,
      Wi2T, nullptr, nullptr, nullptr, Wi2T, nullptr, nullptr, nullptr);
  fold_red_k<<<dim3(2048), 256, 0, stream>>>(partF, Wfold);

  // S1 on [p;n;m] in ONE grouped dispatch (M=3B, K=384): by<2MT -> Wi1, else Wm1
  gemm128_k<0, 0><<<dim3(4, 3 * MT), 512, 0, stream>>>(
      Ain, 12, 384, ACT0, 1024, 1024, part, 2 * MT, 0, 0,
      Wi1p, bi1, nullptr, nullptr, Wm1p, bm1, nullptr, nullptr);
  // stats: 768 partial rows -> 12 chunk rows -> 3 (sc,sh) sets (4 chunks ea)
  bn_red_k<<<dim3(4, 12), 256, 0, stream>>>(part, part2);
  bn_fin3_k<<<dim3(4, 3), 256, 0, stream>>>(
      part2, 4, invB,
      gi1, bti1, scP1, shP1, gi1, bti1, scN1, shN1, gm1, btm1, scM1, shM1);

  // folded img layers 2+3: BN+ReLU fused on A, grouped per branch-half -> d_out
  gemm128_k<2, 1><<<dim3(2, 2 * MT), 512, 0, stream>>>(
      ACT0, 32, 1024, outP, 300, 300, part, MT, 0, 0,
      Wfold, bfold, scP1, shP1, Wfold, bfold, scN1, shN1);

  // mm branch
  gemm128_k<0, 1><<<dim3(4, MT), 512, 0, stream>>>(
      ACT0m, 32, 1024, ACT1m, 1024, 1024, part, BIG, 0, 0,
      Wm2p, bm2, scM1, shM1, Wm2p, bm2, scM1, shM1);
  bn_red_k<<<dim3(4, 4), 256, 0, stream>>>(part, part2);
  bn_fin_k<<<dim3(4), 256, 0, stream>>>(part2, 0, 4, gm2, btm2, scM2, shM2, invB);
  gemm128_k<0, 1><<<dim3(4, MT), 512, 0, stream>>>(
      ACT1m, 32, 1024, ACT0, 1024, 1024, part, BIG, 0, 0,
      Wm3p, bm3, scM2, shM2, Wm3p, bm3, scM2, shM2);
  bn_red_k<<<dim3(4, 4), 256, 0, stream>>>(part, part2);
  bn_fin_k<<<dim3(4), 256, 0, stream>>>(part2, 0, 4, gm3, btm3, scM3, shM3, invB);
  gemm128_k<2, 1><<<dim3(2, MT), 512, 0, stream>>>(
      ACT0, 32, 1024, outA, 300, 300, part, BIG, 0, 0,
      Wm4p, bm4, scM3, shM3, Wm4p, bm4, scM3, shM3);

  // pairwise distances + margin count
  zero_i32<<<1, 64, 0, stream>>>(cnt);
  count_k<<<dim3(1024), 256, 0, stream>>>(outP, outN, outA, B, cnt);
  write_cnt_k<<<1, 64, 0, stream>>>(cnt, outC);
}